// Round 2
// baseline (30.977 us; speedup 1.0000x reference)
//
#include <hip/hip_runtime.h>
#include <math.h>

#define Bn 16
#define Nn 3072
#define Cn 192
#define TOLf 1e-4f
#define MAX_IT 100
#define EPSf 1e-12f
#define RCP(x) __builtin_amdgcn_rcpf(x)

// ---- one PCR step over virtual index v = 3*lane + r, system size Cn=192 ----
// Neighbor v-S lives at register component rm = ((r-S) mod 3) of lane l+offm,
// both compile-time per (r,S): cross-lane via __shfl (ds_bpermute, no barrier).
template<int S>
__device__ __forceinline__ void pcr_step(int l, float* a, float* b, float* c, float* d) {
    float na[3], nb[3], nc[3], nd[3];
#pragma unroll
    for (int r = 0; r < 3; ++r) {
        const int v = 3 * l + r;
        // minus neighbor (v - S)
        const int rm   = (((r - S) % 3) + 3) % 3;
        const int offm = (r - S - rm) / 3;
        float am, bm, cm, dm;
        if (offm == 0) { am = a[rm]; bm = b[rm]; cm = c[rm]; dm = d[rm]; }
        else {
            const int src = l + offm;
            am = __shfl(a[rm], src); bm = __shfl(b[rm], src);
            cm = __shfl(c[rm], src); dm = __shfl(d[rm], src);
        }
        const bool okm = (v - S) >= 0;
        am = okm ? am : 0.f; bm = okm ? bm : 1.f;
        cm = okm ? cm : 0.f; dm = okm ? dm : 0.f;
        // plus neighbor (v + S)
        const int rp   = (r + S) % 3;
        const int offp = (r + S - rp) / 3;
        float ap, bp, cp, dp;
        if (offp == 0) { ap = a[rp]; bp = b[rp]; cp = c[rp]; dp = d[rp]; }
        else {
            const int src = l + offp;
            ap = __shfl(a[rp], src); bp = __shfl(b[rp], src);
            cp = __shfl(c[rp], src); dp = __shfl(d[rp], src);
        }
        const bool okp = (v + S) < Cn;
        ap = okp ? ap : 0.f; bp = okp ? bp : 1.f;
        cp = okp ? cp : 0.f; dp = okp ? dp : 0.f;

        const float alpha = -a[r] * RCP(bm);
        const float gamma = -c[r] * RCP(bp);
        na[r] = alpha * am;
        nc[r] = gamma * cp;
        nb[r] = b[r] + alpha * cm + gamma * ap;
        nd[r] = d[r] + alpha * dm + gamma * dp;
    }
#pragma unroll
    for (int r = 0; r < 3; ++r) { a[r] = na[r]; b[r] = nb[r]; c[r] = nc[r]; d[r] = nd[r]; }
}

// residual + tridiagonal row for one constraint (all scalar args -> registers)
__device__ __forceinline__ void row_one(
    float bd0, float bd1, float bd2, float ii, float ij,
    float f0, float f1, float f2, float fn0, float fn1, float fn2,
    float ji0, float ji1, float ji2, float jj0, float jj1, float jj2,
    float jm0, float jm1, float jm2, float jp0, float jp1, float jp2,
    bool subok, bool supok, float cen,
    float& dd, float& ra, float& rb, float& rc, float& rd, bool& flag)
{
    const float dx = bd0 + ii * f0 - ij * fn0;
    const float dy = bd1 + ii * f1 - ij * fn1;
    const float dz = bd2 + ii * f2 - ij * fn2;
    const float dc = sqrtf(dx * dx + dy * dy + dz * dz + EPSf);
    const float inv = RCP(dc);
    dd = dc;
    const float con = dc - cen;
    flag = flag || (fabsf(con) >= TOLf);
    const float gx = -ii * ji0 + ij * jj0;
    const float gy = -ii * ji1 + ij * jj1;
    const float gz = -ii * ji2 + ij * jj2;
    rb = (dx * gx + dy * gy + dz * gz) * inv;
    ra = subok ? (-ii * (dx * jm0 + dy * jm1 + dz * jm2) * inv) : 0.f;
    rc = supok ? ( ij * (dx * jp0 + dy * jp1 + dz * jp2) * inv) : 0.f;
    rd = con;
}

__global__ __launch_bounds__(256) void bme_fused(
    const float* __restrict__ pos, const float* __restrict__ mom,
    const float* __restrict__ mas, const float* __restrict__ dtm,
    const float* __restrict__ col_jac, const float* __restrict__ col_cen,
    const float* __restrict__ lmd_tmp,
    float* __restrict__ out_pos, float* __restrict__ out_mom,
    float* __restrict__ out_lmd, float* __restrict__ out_con)
{
    const int tid = threadIdx.x;

    if (blockIdx.x >= Bn) {
        // ---- independent tail copy: per batch floats [580, 9216) of pos & mom ----
        const int NT4 = (Nn * 3 - 580) / 4;   // 2159 float4 per batch per array
        const int TOT = Bn * NT4;             // 34544
        const float4* p4 = (const float4*)pos;
        const float4* m4 = (const float4*)mom;
        float4* op4 = (float4*)out_pos;
        float4* om4 = (float4*)out_mom;
        const int nthreads = (256 - Bn) * 256;
        for (int w = (blockIdx.x - Bn) * 256 + tid; w < 2 * TOT; w += nthreads) {
            const int arr = (w >= TOT);
            const int v = arr ? (w - TOT) : w;
            const int batch = v / NT4;
            const int k = v - batch * NT4;
            const size_t off4 = (size_t)batch * (Nn * 3 / 4) + 145 + k;
            if (arr) om4[off4] = m4[off4];
            else     op4[off4] = p4[off4];
        }
        return;
    }

    const int b = blockIdx.x;
    __shared__ float s_lmd[Cn], s_dst[Cn];
    __shared__ float s_frc[Cn + 1][3];

    const float dt  = dtm[b];
    const float dt2 = dt * dt;

    if (tid < 64) {
        const int l = tid;
        float jI[3][3], jJ[3][3], bD[3][3];
        float iI[3], iJ[3], ce[3], lm[3];
#pragma unroll
        for (int r = 0; r < 3; ++r) {
            const int c = 3 * l + r;
            const size_t jb = ((size_t)(b * Cn + c)) * Nn;
#pragma unroll
            for (int k = 0; k < 3; ++k) {
                jI[r][k] = col_jac[(jb + c) * 3 + k];
                jJ[r][k] = col_jac[(jb + c + 1) * 3 + k];
                bD[r][k] = pos[((size_t)b * Nn + c) * 3 + k]
                         - pos[((size_t)b * Nn + c + 1) * 3 + k];
            }
            iI[r] = dt2 / mas[b * Nn + c];
            iJ[r] = dt2 / mas[b * Nn + c + 1];
            ce[r] = col_cen[b * Cn + c];
            lm[r] = 0.f;
        }
        // neighbor jac rows (static): jacI[3l+3] from lane l+1, jacJ[3l-1] from lane l-1
        float jIn[3], jJp[3];
#pragma unroll
        for (int k = 0; k < 3; ++k) {
            jIn[k] = __shfl(jI[0][k], l + 1);
            jJp[k] = __shfl(jJ[2][k], l - 1);
        }

        float dd[3], frc[3][3], frcN[3];
        float rA[3], rB[3], rC[3], rD[3];
        int it = 0;
        while (true) {
            const float lmp = (l == 0)  ? 0.f : __shfl(lm[2], l - 1);
            const float lmn = (l == 63) ? 0.f : __shfl(lm[0], l + 1);
            // forces on atoms v = 3l+r and 3l+3:  frc[a] = -(lmd[a]*jacI[a] + lmd[a-1]*jacJ[a-1])
#pragma unroll
            for (int k = 0; k < 3; ++k) {
                frc[0][k] = -(lm[0] * jI[0][k] + lmp    * jJp[k]);
                frc[1][k] = -(lm[1] * jI[1][k] + lm[0] * jJ[0][k]);
                frc[2][k] = -(lm[2] * jI[2][k] + lm[1] * jJ[1][k]);
                frcN[k]   = -(lmn   * jIn[k]   + lm[2] * jJ[2][k]);
            }
            bool flag = false;
            row_one(bD[0][0], bD[0][1], bD[0][2], iI[0], iJ[0],
                    frc[0][0], frc[0][1], frc[0][2], frc[1][0], frc[1][1], frc[1][2],
                    jI[0][0], jI[0][1], jI[0][2], jJ[0][0], jJ[0][1], jJ[0][2],
                    jJp[0], jJp[1], jJp[2], jI[1][0], jI[1][1], jI[1][2],
                    l > 0, true, ce[0],
                    dd[0], rA[0], rB[0], rC[0], rD[0], flag);
            row_one(bD[1][0], bD[1][1], bD[1][2], iI[1], iJ[1],
                    frc[1][0], frc[1][1], frc[1][2], frc[2][0], frc[2][1], frc[2][2],
                    jI[1][0], jI[1][1], jI[1][2], jJ[1][0], jJ[1][1], jJ[1][2],
                    jJ[0][0], jJ[0][1], jJ[0][2], jI[2][0], jI[2][1], jI[2][2],
                    true, true, ce[1],
                    dd[1], rA[1], rB[1], rC[1], rD[1], flag);
            row_one(bD[2][0], bD[2][1], bD[2][2], iI[2], iJ[2],
                    frc[2][0], frc[2][1], frc[2][2], frcN[0], frcN[1], frcN[2],
                    jI[2][0], jI[2][1], jI[2][2], jJ[2][0], jJ[2][1], jJ[2][2],
                    jJ[1][0], jJ[1][1], jJ[1][2], jIn[0], jIn[1], jIn[2],
                    true, l < 63, ce[2],
                    dd[2], rA[2], rB[2], rC[2], rD[2], flag);

            if (!__any(flag) || it >= MAX_IT) break;

            pcr_step<1>(l, rA, rB, rC, rD);
            pcr_step<2>(l, rA, rB, rC, rD);
            pcr_step<4>(l, rA, rB, rC, rD);
            pcr_step<8>(l, rA, rB, rC, rD);
            pcr_step<16>(l, rA, rB, rC, rD);
            pcr_step<32>(l, rA, rB, rC, rD);
            pcr_step<64>(l, rA, rB, rC, rD);
            pcr_step<128>(l, rA, rB, rC, rD);
#pragma unroll
            for (int r = 0; r < 3; ++r) lm[r] -= rD[r] * RCP(rB[r]);
            ++it;
        }
        // publish: lmd, final distances, final forces on chain atoms
#pragma unroll
        for (int r = 0; r < 3; ++r) {
            const int c = 3 * l + r;
            s_lmd[c] = lm[r];
            s_dst[c] = dd[r];
            s_frc[c][0] = frc[r][0]; s_frc[c][1] = frc[r][1]; s_frc[c][2] = frc[r][2];
        }
        if (l == 63) { s_frc[Cn][0] = frcN[0]; s_frc[Cn][1] = frcN[1]; s_frc[Cn][2] = frcN[2]; }
    }
    __syncthreads();

    // ---- epilogue: all 256 threads ----
    if (tid < Cn) {
        const int o = b * Cn + tid;
        out_lmd[o] = lmd_tmp[o] + s_lmd[tid];
        out_con[o] = s_dst[tid];
    }
    if (tid <= Cn) {                      // atoms 0..192 carry force
        const size_t p  = ((size_t)b * Nn + tid) * 3;
        const float  im = dt2 / mas[b * Nn + tid];
        out_pos[p + 0] = pos[p + 0] + s_frc[tid][0] * im;
        out_pos[p + 1] = pos[p + 1] + s_frc[tid][1] * im;
        out_pos[p + 2] = pos[p + 2] + s_frc[tid][2] * im;
        out_mom[p + 0] = mom[p + 0] + s_frc[tid][0] * dt;
        out_mom[p + 1] = mom[p + 1] + s_frc[tid][1] * dt;
        out_mom[p + 2] = mom[p + 2] + s_frc[tid][2] * dt;
    } else if (tid == Cn + 1) {           // float 579 (atom 193, x) is a pure copy
        const size_t e = (size_t)b * Nn * 3 + 579;
        out_pos[e] = pos[e];
        out_mom[e] = mom[e];
    }
}

extern "C" void kernel_launch(void* const* d_in, const int* in_sizes, int n_in,
                              void* d_out, int out_size, void* d_ws, size_t ws_size,
                              hipStream_t stream) {
    const float* pos     = (const float*)d_in[0];
    const float* mom     = (const float*)d_in[1];
    const float* mas     = (const float*)d_in[2];
    const float* dtm     = (const float*)d_in[3];
    const float* col_jac = (const float*)d_in[4];
    const float* col_cen = (const float*)d_in[5];
    const float* lmd_tmp = (const float*)d_in[6];

    float* out     = (float*)d_out;
    float* out_pos = out;                            // [B,N,3]
    float* out_mom = out + (size_t)Bn * Nn * 3;      // [B,N,3]
    float* out_lmd = out + (size_t)2 * Bn * Nn * 3;  // [B,C]
    float* out_con = out_lmd + Bn * Cn;              // [B,C]

    bme_fused<<<256, 256, 0, stream>>>(pos, mom, mas, dtm, col_jac, col_cen,
                                       lmd_tmp, out_pos, out_mom, out_lmd, out_con);
}

// Round 3
// 11.445 us; speedup vs baseline: 2.7068x; 2.7068x over previous
//
#include <hip/hip_runtime.h>
#include <math.h>

#define Bn 16
#define Nn 3072
#define Cn 192
#define TOLf 1e-4f
#define MAX_IT 100
#define EPSf 1e-12f
#define RCP(x) __builtin_amdgcn_rcpf(x)
#define OFS 128   // LDS pad offset: indices [-128, 384) -> [0, 512)

// One solver block per batch (blocks 0..15); blocks 16..255 do the tail copy.
// Solver: 192 constraint threads + 64 identity-pad threads.
// Quasi-Newton: full PCR once (recording alpha/gamma + 1/b), then cheap
// RHS-only replays; factorization refreshed every 8 iterations.
__global__ __launch_bounds__(256) void bme_fused(
    const float* __restrict__ pos, const float* __restrict__ mom,
    const float* __restrict__ mas, const float* __restrict__ dtm,
    const float* __restrict__ col_jac, const float* __restrict__ col_cen,
    const float* __restrict__ lmd_tmp,
    float* __restrict__ out_pos, float* __restrict__ out_mom,
    float* __restrict__ out_lmd, float* __restrict__ out_con)
{
    const int tid = threadIdx.x;

    if (blockIdx.x >= Bn) {
        // ---- independent tail copy: per batch floats [580, 9216) of pos & mom ----
        const int NT4 = (Nn * 3 - 580) / 4;   // 2159 float4 per batch per array
        const int TOT = Bn * NT4;
        const float4* p4 = (const float4*)pos;
        const float4* m4 = (const float4*)mom;
        float4* op4 = (float4*)out_pos;
        float4* om4 = (float4*)out_mom;
        const int nthreads = (256 - Bn) * 256;
        for (int w = (blockIdx.x - Bn) * 256 + tid; w < 2 * TOT; w += nthreads) {
            const int arr = (w >= TOT);
            const int v = arr ? (w - TOT) : w;
            const int batch = v / NT4;
            const int k = v - batch * NT4;
            const size_t off4 = (size_t)batch * (Nn * 3 / 4) + 145 + k;
            if (arr) om4[off4] = m4[off4];
            else     op4[off4] = p4[off4];
        }
        return;
    }

    const int b    = blockIdx.x;
    const int c    = tid;          // constraint id; c >= Cn are identity pads
    const int lane = tid & 63;
    const int wid  = tid >> 6;

    __shared__ float4 rows[2][512];   // (a, b, c, d) PCR rows, padded
    __shared__ float  dbuf[2][512];   // RHS replay buffers, padded
    __shared__ float  invbL[512];     // frozen 1/b_final, padded with 1
    __shared__ int    flagL[4];

    {   // init pads/identities (outer pad regions are never written again)
        const float4 ident = make_float4(0.f, 1.f, 0.f, 0.f);
        rows[0][tid] = ident; rows[0][tid + 256] = ident;
        rows[1][tid] = ident; rows[1][tid + 256] = ident;
        dbuf[0][tid] = 0.f;  dbuf[0][tid + 256] = 0.f;
        dbuf[1][tid] = 0.f;  dbuf[1][tid + 256] = 0.f;
        invbL[tid]   = 1.f;  invbL[tid + 256]   = 1.f;
        if (tid < 4) flagL[tid] = 0;
    }

    const float dt  = dtm[b];
    const float dt2 = dt * dt;

    float jI[3]  = {0,0,0}, jJ[3]  = {0,0,0};
    float jJm[3] = {0,0,0}, jIp[3] = {0,0,0};
    float bD[3]  = {0,0,0};
    float imI = 0.f, imJ = 0.f, cen = 0.f;
    if (c < Cn) {
        const size_t rb0 = ((size_t)(b * Cn + c)) * Nn;
#pragma unroll
        for (int k = 0; k < 3; ++k) {
            jI[k] = col_jac[(rb0 + c) * 3 + k];          // jac of con c at atom c
            jJ[k] = col_jac[(rb0 + c + 1) * 3 + k];      // jac of con c at atom c+1
            bD[k] = pos[((size_t)b * Nn + c) * 3 + k]
                  - pos[((size_t)b * Nn + c + 1) * 3 + k];
        }
        if (c > 0) {
            const size_t rbm = ((size_t)(b * Cn + c - 1)) * Nn;
#pragma unroll
            for (int k = 0; k < 3; ++k) jJm[k] = col_jac[(rbm + c) * 3 + k];
        }
        if (c < Cn - 1) {
            const size_t rbp = ((size_t)(b * Cn + c + 1)) * Nn;
#pragma unroll
            for (int k = 0; k < 3; ++k) jIp[k] = col_jac[(rbp + c + 1) * 3 + k];
        }
        imI = dt2 / mas[b * Nn + c];
        imJ = dt2 / mas[b * Nn + c + 1];
        cen = col_cen[b * Cn + c];
    }
    __syncthreads();   // init + loads visible before any LDS reuse

    float lmd_m = 0.f, lmd_c = 0.f, lmd_p = 0.f;  // lmd[c-1], lmd[c], lmd[c+1]
    float alph[8], gamm[8];                        // frozen PCR coefficients
    float fi[3] = {0,0,0}, fj[3] = {0,0,0};        // forces on atoms c, c+1
    float dist = 0.f;
    int it = 0;

    while (true) {
        // ---- residual at current lmd ----
        float con = 0.f;
        float dxv[3] = {0,0,0};
        if (c < Cn) {
#pragma unroll
            for (int k = 0; k < 3; ++k) {
                fi[k]  = -(lmd_c * jI[k]  + lmd_m * jJm[k]);
                fj[k]  = -(lmd_p * jIp[k] + lmd_c * jJ[k]);
                dxv[k] = bD[k] + imI * fi[k] - imJ * fj[k];
            }
            dist = sqrtf(dxv[0]*dxv[0] + dxv[1]*dxv[1] + dxv[2]*dxv[2] + EPSf);
            con  = dist - cen;
        }
        const bool refresh = ((it & 7) == 0);
        const int  wf = __any(fabsf(con) >= TOLf);
        if (lane == 0) flagL[wid] = wf;

        float ra = 0.f, rb2 = 1.f, rc2 = 0.f;   // tridiagonal row (pads: identity)
        if (refresh) {
            if (c < Cn) {
                const float inv = RCP(dist);
                const float gx = -imI * jI[0] + imJ * jJ[0];
                const float gy = -imI * jI[1] + imJ * jJ[1];
                const float gz = -imI * jI[2] + imJ * jJ[2];
                rb2 = (dxv[0]*gx + dxv[1]*gy + dxv[2]*gz) * inv;
                if (c > 0)
                    ra = -imI * (dxv[0]*jJm[0] + dxv[1]*jJm[1] + dxv[2]*jJm[2]) * inv;
                if (c < Cn - 1)
                    rc2 =  imJ * (dxv[0]*jIp[0] + dxv[1]*jIp[1] + dxv[2]*jIp[2]) * inv;
            }
            rows[0][tid + OFS] = make_float4(ra, rb2, rc2, con);
        } else {
            dbuf[0][tid + OFS] = con;
        }
        __syncthreads();

        const int go = flagL[0] | flagL[1] | flagL[2] | flagL[3];
        if (!go || it >= MAX_IT) break;      // dist/fi/fj are at final lmd

        float dr, dm1, dp1;
        if (refresh) {
            // ---- full PCR, record alpha/gamma, update frozen invb ----
            dr = con;
            int p = 0;
#pragma unroll
            for (int s = 0; s < 8; ++s) {
                const int S = 1 << s;
                const float4 m  = rows[p][tid - S + OFS];
                const float4 pl = rows[p][tid + S + OFS];
                const float alpha = -ra  * RCP(m.y);
                const float gamma = -rc2 * RCP(pl.y);
                alph[s] = alpha; gamm[s] = gamma;
                const float na = alpha * m.x;
                const float nc = gamma * pl.z;
                const float nb = rb2 + alpha * m.z + gamma * pl.x;
                const float nd = dr  + alpha * m.w + gamma * pl.w;
                rows[p ^ 1][tid + OFS] = make_float4(na, nb, nc, nd);
                ra = na; rb2 = nb; rc2 = nc; dr = nd;
                __syncthreads();
                p ^= 1;
            }
            invbL[tid + OFS] = RCP(rb2);
            __syncthreads();                 // publish invb for neighbor reads
            dm1 = rows[p][tid - 1 + OFS].w;
            dp1 = rows[p][tid + 1 + OFS].w;
        } else {
            // ---- cheap RHS-only replay of the frozen factorization ----
            dr = con;
            int q = 0;
#pragma unroll
            for (int s = 0; s < 8; ++s) {
                const int S = 1 << s;
                const float dm = dbuf[q][tid - S + OFS];
                const float dp = dbuf[q][tid + S + OFS];
                dr += alph[s] * dm + gamm[s] * dp;
                dbuf[q ^ 1][tid + OFS] = dr;
                __syncthreads();
                q ^= 1;
            }
            dm1 = dbuf[q][tid - 1 + OFS];
            dp1 = dbuf[q][tid + 1 + OFS];
        }

        // ---- Newton update for lmd[c-1], lmd[c], lmd[c+1] (all in regs) ----
        lmd_m -= dm1 * invbL[tid - 1 + OFS];
        lmd_c -= dr  * invbL[tid + OFS];
        lmd_p -= dp1 * invbL[tid + 1 + OFS];
        ++it;
        __syncthreads();   // protect this iter's neighbor reads from next writes
    }

    // ---- epilogue: outputs ----
    if (c < Cn) {
        const int o = b * Cn + c;
        out_lmd[o] = lmd_tmp[o] + lmd_c;
        out_con[o] = dist;
        const size_t pp = ((size_t)b * Nn + c) * 3;
#pragma unroll
        for (int k = 0; k < 3; ++k) {
            out_pos[pp + k] = pos[pp + k] + fi[k] * imI;
            out_mom[pp + k] = mom[pp + k] + fi[k] * dt;
        }
        if (c == Cn - 1) {                    // atom Cn carries only fj of con Cn-1
            const size_t pq = ((size_t)b * Nn + Cn) * 3;
#pragma unroll
            for (int k = 0; k < 3; ++k) {
                out_pos[pq + k] = pos[pq + k] + fj[k] * imJ;
                out_mom[pq + k] = mom[pq + k] + fj[k] * dt;
            }
        }
    } else if (tid == Cn + 1) {               // float 579 (atom 193, x) pure copy
        const size_t e = (size_t)b * Nn * 3 + 579;
        out_pos[e] = pos[e];
        out_mom[e] = mom[e];
    }
}

extern "C" void kernel_launch(void* const* d_in, const int* in_sizes, int n_in,
                              void* d_out, int out_size, void* d_ws, size_t ws_size,
                              hipStream_t stream) {
    const float* pos     = (const float*)d_in[0];
    const float* mom     = (const float*)d_in[1];
    const float* mas     = (const float*)d_in[2];
    const float* dtm     = (const float*)d_in[3];
    const float* col_jac = (const float*)d_in[4];
    const float* col_cen = (const float*)d_in[5];
    const float* lmd_tmp = (const float*)d_in[6];

    float* out     = (float*)d_out;
    float* out_pos = out;                            // [B,N,3]
    float* out_mom = out + (size_t)Bn * Nn * 3;      // [B,N,3]
    float* out_lmd = out + (size_t)2 * Bn * Nn * 3;  // [B,C]
    float* out_con = out_lmd + Bn * Cn;              // [B,C]

    bme_fused<<<256, 256, 0, stream>>>(pos, mom, mas, dtm, col_jac, col_cen,
                                       lmd_tmp, out_pos, out_mom, out_lmd, out_con);
}

// Round 4
// 9.770 us; speedup vs baseline: 3.1706x; 1.1714x over previous
//
#include <hip/hip_runtime.h>
#include <math.h>

#define Bn 16
#define Nn 3072
#define Cn 192
#define EPSf 1e-12f
#define RCP(x) __builtin_amdgcn_rcpf(x)
#define OFS 128   // LDS pad offset: virtual indices [-128, 384) -> [0, 512)

// Blocks 0..15: one per batch. Fixed Newton schedule (no convergence flags):
//   solve 0: analytic tridiagonal J at lmd=0 (residual free: con0 = |bD| - cen),
//            6 PCR steps (recording alpha/gamma) + 3x3 Thomas chain solve
//            (recording multipliers).
//   solve 1: residual -> RHS-only replay of the frozen factorization.
//   final  : residual once more for out_con/forces.
// Blocks 16..255: tail copy of pos/mom for atoms > Cn (zero force there).
__global__ __launch_bounds__(256) void bme_fused(
    const float* __restrict__ pos, const float* __restrict__ mom,
    const float* __restrict__ mas, const float* __restrict__ dtm,
    const float* __restrict__ col_jac, const float* __restrict__ col_cen,
    const float* __restrict__ lmd_tmp,
    float* __restrict__ out_pos, float* __restrict__ out_mom,
    float* __restrict__ out_lmd, float* __restrict__ out_con)
{
    const int tid = threadIdx.x;

    if (blockIdx.x >= Bn) {
        // ---- independent tail copy: per batch floats [580, 9216) of pos & mom ----
        const int NT4 = (Nn * 3 - 580) / 4;   // 2159 float4 per batch per array
        const int TOT = Bn * NT4;
        const float4* p4 = (const float4*)pos;
        const float4* m4 = (const float4*)mom;
        float4* op4 = (float4*)out_pos;
        float4* om4 = (float4*)out_mom;
        const int nthreads = (256 - Bn) * 256;
        for (int w = (blockIdx.x - Bn) * 256 + tid; w < 2 * TOT; w += nthreads) {
            const int arr = (w >= TOT);
            const int v = arr ? (w - TOT) : w;
            const int batch = v / NT4;
            const int k = v - batch * NT4;
            const size_t off4 = (size_t)batch * (Nn * 3 / 4) + 145 + k;
            if (arr) om4[off4] = m4[off4];
            else     op4[off4] = p4[off4];
        }
        return;
    }

    const int b = blockIdx.x;
    const int c = tid;                 // constraint id; c >= Cn are identity pads

    __shared__ float4 rows[2][512];    // PCR rows (a,b,c,d), padded both buffers
    __shared__ float  dbuf[2][512];    // RHS replay buffers, padded
    __shared__ float  s_jac[194][6];   // [1+c] = (jI[3], jJ[3]) of constraint c
    __shared__ float  s_pm[194][5];    // [a] = (pos[3], mas) of atom a (stride 5: no bank conflict)
    __shared__ float  lmd_s[194];      // [1+c] = lmd[c]; [0], [193] stay 0

    // ---- init pads (outer pad regions are never written again) ----
    {
        const float4 ident = make_float4(0.f, 1.f, 0.f, 0.f);
        rows[0][tid] = ident; rows[0][tid + 256] = ident;
        rows[1][tid] = ident; rows[1][tid + 256] = ident;
        dbuf[0][tid] = 0.f;  dbuf[0][tid + 256] = 0.f;
        dbuf[1][tid] = 0.f;  dbuf[1][tid + 256] = 0.f;
        if (tid < 194) lmd_s[tid] = 0.f;
        if (tid < 6) { s_jac[0][tid] = 0.f; s_jac[193][tid] = 0.f; }
    }

    const float dt  = dtm[b];
    const float dt2 = dt * dt;

    // ---- gather: each constraint's 6 contiguous jac floats; each atom's pos+mas ----
    float cen = 0.f;
    if (c < Cn) {
        const size_t rb0 = ((size_t)(b * Cn + c)) * Nn;
        const float* src = &col_jac[(rb0 + c) * 3];   // jI (atom c) then jJ (atom c+1)
#pragma unroll
        for (int k = 0; k < 6; ++k) s_jac[c + 1][k] = src[k];
        cen = col_cen[b * Cn + c];
    }
    if (tid <= Cn) {                                  // atom tid in [0, 192]
        const size_t pa = ((size_t)b * Nn + tid) * 3;
#pragma unroll
        for (int k = 0; k < 3; ++k) s_pm[tid][k] = pos[pa + k];
        s_pm[tid][3] = mas[b * Nn + tid];
    }
    __syncthreads();

    // ---- per-thread registers from shared ----
    float jI[3] = {0,0,0}, jJ[3] = {0,0,0}, jJm[3] = {0,0,0}, jIp[3] = {0,0,0};
    float bD[3] = {0,0,0};
    float imI = 0.f, imJ = 0.f;
    if (c < Cn) {
#pragma unroll
        for (int k = 0; k < 3; ++k) {
            jI[k]  = s_jac[c + 1][k];
            jJ[k]  = s_jac[c + 1][3 + k];
            jJm[k] = s_jac[c][3 + k];       // jJ of constraint c-1 (zeros at c=0)
            jIp[k] = s_jac[c + 2][k];       // jI of constraint c+1 (zeros at c=191)
            bD[k]  = s_pm[c][k] - s_pm[c + 1][k];
        }
        imI = dt2 / s_pm[c][3];
        imJ = dt2 / s_pm[c + 1][3];
    }

    // ---- solve 0: rows of J at lmd = 0 (dxv == bD), RHS = con0 ----
    float ra = 0.f, rb2 = 1.f, rc2 = 0.f, rd = 0.f;
    if (c < Cn) {
        const float dist0 = sqrtf(bD[0]*bD[0] + bD[1]*bD[1] + bD[2]*bD[2] + EPSf);
        const float inv   = RCP(dist0);
        rd  = dist0 - cen;
        const float gx = -imI * jI[0] + imJ * jJ[0];
        const float gy = -imI * jI[1] + imJ * jJ[1];
        const float gz = -imI * jI[2] + imJ * jJ[2];
        rb2 = (bD[0]*gx + bD[1]*gy + bD[2]*gz) * inv;
        if (c > 0)
            ra  = -imI * (bD[0]*jJm[0] + bD[1]*jJm[1] + bD[2]*jJm[2]) * inv;
        if (c < Cn - 1)
            rc2 =  imJ * (bD[0]*jIp[0] + bD[1]*jIp[1] + bD[2]*jIp[2]) * inv;
    }
    rows[0][tid + OFS] = make_float4(ra, rb2, rc2, rd);
    __syncthreads();

    // ---- 6 PCR steps, recording alpha/gamma ----
    float al[6], ga[6];
    {
        float a = ra, bb = rb2, cc = rc2, dd = rd;
        int p = 0;
#pragma unroll
        for (int s = 0; s < 6; ++s) {
            const int S = 1 << s;
            const float4 m  = rows[p][tid - S + OFS];
            const float4 pl = rows[p][tid + S + OFS];
            al[s] = -a  * RCP(m.y);
            ga[s] = -cc * RCP(pl.y);
            const float na = al[s] * m.x;
            const float nc = ga[s] * pl.z;
            const float nb = bb + al[s] * m.z + ga[s] * pl.x;
            const float nd = dd + al[s] * m.w + ga[s] * pl.w;
            rows[p ^ 1][tid + OFS] = make_float4(na, nb, nc, nd);
            __syncthreads();
            a = na; bb = nb; cc = nc; dd = nd; p ^= 1;
        }
    }
    // final rows in rows[0]; couplings now at +-64: 64 independent 3-chains

    // ---- 3x3 Thomas per chain {t, t+64, t+128}, record multipliers ----
    float m1 = 0.f, m2 = 0.f, ib0 = 0.f, ib1 = 0.f, ib2 = 0.f, cc0 = 0.f, cc1 = 0.f;
    if (tid < 64) {
        const float4 r0 = rows[0][tid + OFS];
        const float4 r1 = rows[0][tid + 64 + OFS];
        const float4 r2 = rows[0][tid + 128 + OFS];
        ib0 = RCP(r0.y);
        m1  = r1.x * ib0;
        const float b1p = r1.y - m1 * r0.z;  ib1 = RCP(b1p);
        const float d1p = r1.w - m1 * r0.w;
        m2  = r2.x * ib1;
        const float b2p = r2.y - m2 * r1.z;  ib2 = RCP(b2p);
        const float d2p = r2.w - m2 * d1p;
        cc0 = r0.z; cc1 = r1.z;
        const float y2 = d2p * ib2;
        const float y1 = (d1p - cc1 * y2) * ib1;
        const float y0 = (r0.w - cc0 * y1) * ib0;
        lmd_s[1 + tid]       -= y0;
        lmd_s[1 + tid + 64]  -= y1;
        lmd_s[1 + tid + 128] -= y2;
    }
    __syncthreads();

    // ---- solve 1: residual -> frozen-factorization replay ----
    {
        float con = 0.f;
        if (c < Cn) {
            const float lm_m = lmd_s[c], lm_c = lmd_s[c + 1], lm_p = lmd_s[c + 2];
            float dxv[3];
#pragma unroll
            for (int k = 0; k < 3; ++k) {
                const float fik = -(lm_c * jI[k]  + lm_m * jJm[k]);
                const float fjk = -(lm_p * jIp[k] + lm_c * jJ[k]);
                dxv[k] = bD[k] + imI * fik - imJ * fjk;
            }
            const float d1 = sqrtf(dxv[0]*dxv[0] + dxv[1]*dxv[1] + dxv[2]*dxv[2] + EPSf);
            con = d1 - cen;
        }
        dbuf[0][tid + OFS] = con;
        __syncthreads();

        float dr = con;
        int q = 0;
#pragma unroll
        for (int s = 0; s < 6; ++s) {
            const int S = 1 << s;
            const float dm = dbuf[q][tid - S + OFS];
            const float dp = dbuf[q][tid + S + OFS];
            dr += al[s] * dm + ga[s] * dp;
            dbuf[q ^ 1][tid + OFS] = dr;
            __syncthreads();
            q ^= 1;
        }
        if (tid < 64) {
            const float d0r = dbuf[0][tid + OFS];
            const float d1r = dbuf[0][tid + 64 + OFS];
            const float d2r = dbuf[0][tid + 128 + OFS];
            const float d1p = d1r - m1 * d0r;
            const float d2p = d2r - m2 * d1p;
            const float y2 = d2p * ib2;
            const float y1 = (d1p - cc1 * y2) * ib1;
            const float y0 = (d0r - cc0 * y1) * ib0;
            lmd_s[1 + tid]       -= y0;
            lmd_s[1 + tid + 64]  -= y1;
            lmd_s[1 + tid + 128] -= y2;
        }
        __syncthreads();
    }

    // ---- final residual + epilogue ----
    if (c < Cn) {
        const float lm_m = lmd_s[c], lm_c = lmd_s[c + 1], lm_p = lmd_s[c + 2];
        float fi[3], fj[3], dxv[3];
#pragma unroll
        for (int k = 0; k < 3; ++k) {
            fi[k]  = -(lm_c * jI[k]  + lm_m * jJm[k]);
            fj[k]  = -(lm_p * jIp[k] + lm_c * jJ[k]);
            dxv[k] = bD[k] + imI * fi[k] - imJ * fj[k];
        }
        const float dist = sqrtf(dxv[0]*dxv[0] + dxv[1]*dxv[1] + dxv[2]*dxv[2] + EPSf);

        const int o = b * Cn + c;
        out_lmd[o] = lmd_tmp[o] + lm_c;
        out_con[o] = dist;

        const size_t pp = ((size_t)b * Nn + c) * 3;
#pragma unroll
        for (int k = 0; k < 3; ++k) {
            out_pos[pp + k] = pos[pp + k] + fi[k] * imI;
            out_mom[pp + k] = mom[pp + k] + fi[k] * dt;
        }
        if (c == Cn - 1) {                 // atom Cn carries only fj of constraint Cn-1
            const size_t pq = ((size_t)b * Nn + Cn) * 3;
#pragma unroll
            for (int k = 0; k < 3; ++k) {
                out_pos[pq + k] = pos[pq + k] + fj[k] * imJ;
                out_mom[pq + k] = mom[pq + k] + fj[k] * dt;
            }
        }
    } else if (tid == Cn + 1) {            // float 579 (atom 193, x) pure copy
        const size_t e = (size_t)b * Nn * 3 + 579;
        out_pos[e] = pos[e];
        out_mom[e] = mom[e];
    }
}

extern "C" void kernel_launch(void* const* d_in, const int* in_sizes, int n_in,
                              void* d_out, int out_size, void* d_ws, size_t ws_size,
                              hipStream_t stream) {
    const float* pos     = (const float*)d_in[0];
    const float* mom     = (const float*)d_in[1];
    const float* mas     = (const float*)d_in[2];
    const float* dtm     = (const float*)d_in[3];
    const float* col_jac = (const float*)d_in[4];
    const float* col_cen = (const float*)d_in[5];
    const float* lmd_tmp = (const float*)d_in[6];

    float* out     = (float*)d_out;
    float* out_pos = out;                            // [B,N,3]
    float* out_mom = out + (size_t)Bn * Nn * 3;      // [B,N,3]
    float* out_lmd = out + (size_t)2 * Bn * Nn * 3;  // [B,C]
    float* out_con = out_lmd + Bn * Cn;              // [B,C]

    bme_fused<<<256, 256, 0, stream>>>(pos, mom, mas, dtm, col_jac, col_cen,
                                       lmd_tmp, out_pos, out_mom, out_lmd, out_con);
}